// Round 16
// baseline (176.903 us; speedup 1.0000x reference)
//
#include <hip/hip_runtime.h>
#include <math.h>

#define N_TOK   65536
#define HID     1024
#define NEXP    64
#define EPSF    1e-12f

__device__ __forceinline__ unsigned enc_key(float f) {
    unsigned u = __float_as_uint(f);
    return (u & 0x80000000u) ? ~u : (u | 0x80000000u);
}

// ---------------- prep: ws[0..63] = 1/||sim col||, ws[64..127] = sigmoid(gates)
__global__ __launch_bounds__(256) void prep_kernel(const float* __restrict__ sim,
                                                   const float* __restrict__ gates,
                                                   float* __restrict__ ws) {
    __shared__ float partial[4][64];
    int e = threadIdx.x & 63;
    int q = threadIdx.x >> 6;
    float s = 0.f;
    for (int h = q * 256; h < q * 256 + 256; ++h) {
        float v = sim[h * NEXP + e];
        s += v * v;
    }
    partial[q][e] = s;
    __syncthreads();
    if (threadIdx.x < 64) {
        float ss = partial[0][e] + partial[1][e] + partial[2][e] + partial[3][e];
        ws[e] = 1.0f / fmaxf(sqrtf(ss), EPSF);
        ws[64 + e] = 1.0f / (1.0f + expf(-gates[e]));
    }
}

// ---------------- prep2b: expert-half-major normalized W.
// wn2[(e>>5)*32768 + k*32 + (e&31)] = sim[k*64+e] * invcol[e]
// (single f32 mul — identical rounding to every passing round)
__global__ __launch_bounds__(256) void prep2b_kernel(const float* __restrict__ sim,
                                                     const float* __restrict__ ws_ro,
                                                     float* __restrict__ wn2) {
    int idx = blockIdx.x * 256 + threadIdx.x;   // 0..65535
    int k = idx >> 6;
    int e = idx & 63;
    wn2[(size_t)(e >> 5) * 32768 + k * 32 + (e & 31)] = sim[idx] * ws_ro[e];
}

// ---------------- main kernel v15: lane = token, W wave-uniform, no LDS in
// the main loop. Block = 256 thr = 4 waves (kh,eh): wave computes 64 tokens x
// 32 experts x 512 k with acc[32] in VGPRs. x streams per-lane from global
// (own row only — no cross-lane x needed); W rows are wave-uniform 128B/k
// (scalar-cache friendly via readfirstlane'd wave id). K-halves combined via
// one LDS plane at the end; epilogue = v10's hardware-verified path.
__global__ __launch_bounds__(256) void gate_v15_kernel(const float* __restrict__ x,
                                                       const float* __restrict__ wn2,
                                                       const float* __restrict__ prep,
                                                       float* __restrict__ out) {
    // plane [64][68] at 0 (4352), ss_part[2][64] at 4352
    __shared__ __align__(16) float smem[4480];
    float* plane   = smem;
    float* ss_part = smem + 4352;

    const int tid  = threadIdx.x;
    const int lane = tid & 63;
    const int wvu  = __builtin_amdgcn_readfirstlane(tid >> 6);   // scalar wave id
    const int kh   = wvu >> 1;            // k-half
    const int eh   = wvu & 1;             // expert-half
    const int tbase = blockIdx.x * 64;

    const float4* xq = (const float4*)(x + (size_t)(tbase + lane) * HID + kh * 512);
    const float* wb = wn2 + (size_t)eh * 32768 + (size_t)kh * 512 * 32;

    float acc[32];
#pragma unroll
    for (int e = 0; e < 32; ++e) acc[e] = 0.f;
    float ss = 0.f;

    float4 xv0 = xq[0], xv1 = xq[1];

#pragma unroll 1
    for (int c = 0; c < 64; ++c) {        // 64 chunks x 8 k = 512 k
        float4 nx0, nx1;
        if (c < 63) {
            nx0 = xq[(c + 1) * 2];
            nx1 = xq[(c + 1) * 2 + 1];
        }
        const float a[8] = { xv0.x, xv0.y, xv0.z, xv0.w, xv1.x, xv1.y, xv1.z, xv1.w };
        const float* wc = wb + c * 8 * 32;
#pragma unroll
        for (int i = 0; i < 8; ++i) {
            if (eh == 0) ss = fmaf(a[i], a[i], ss);   // wave-uniform branch
            const float* wr = wc + i * 32;            // wave-uniform address
#pragma unroll
            for (int e = 0; e < 32; ++e)
                acc[e] = fmaf(a[i], wr[e], acc[e]);
        }
        xv0 = nx0; xv1 = nx1;
    }

    // ---- combine k-halves ----
    if (eh == 0) ss_part[kh * 64 + lane] = ss;
    if (kh == 0) {
#pragma unroll
        for (int e = 0; e < 32; e += 4)
            *(float4*)&plane[lane * 68 + eh * 32 + e] =
                make_float4(acc[e], acc[e + 1], acc[e + 2], acc[e + 3]);
    }
    __syncthreads();
    if (kh == 1) {
#pragma unroll
        for (int e = 0; e < 32; e += 4) {
            float* p = &plane[lane * 68 + eh * 32 + e];
            float4 v = *(const float4*)p;
            v.x += acc[e]; v.y += acc[e + 1]; v.z += acc[e + 2]; v.w += acc[e + 3];
            *(float4*)p = v;
        }
    }
    __syncthreads();

    // ---- epilogue (v10-verified): wave wvu -> local tokens wvu*16..+15 ----
    const int tg = lane >> 3;
    const int eg = lane & 7;
    const int e0 = eg * 8;
    float thr[8];
#pragma unroll
    for (int i = 0; i < 8; ++i) thr[i] = prep[64 + e0 + i];

    const size_t out_pre  = (size_t)N_TOK * NEXP;
    const size_t out_mask = 2 * (size_t)N_TOK * NEXP;

#pragma unroll
    for (int j = 0; j < 2; ++j) {
        const int tl = wvu * 16 + tg * 2 + j;
        const int t  = tbase + tl;
        const float sst = ss_part[tl] + ss_part[64 + tl];
        const float inv = 1.0f / fmaxf(sqrtf(sst), EPSF);

        float4 l0 = *(const float4*)&plane[tl * 68 + e0];
        float4 l1 = *(const float4*)&plane[tl * 68 + e0 + 4];
        float logit[8] = { l0.x * inv, l0.y * inv, l0.z * inv, l0.w * inv,
                           l1.x * inv, l1.y * inv, l1.z * inv, l1.w * inv };
        float pre[8], gated[8];
        int active[8];
        int myact = 0;
#pragma unroll
        for (int i = 0; i < 8; ++i) {
            pre[i]   = logit[i] - thr[i];
            gated[i] = fmaxf(pre[i], 0.f);
            active[i] = pre[i] > 0.f;
            myact += active[i];
        }
        int rowact = myact;
        rowact += __shfl_xor(rowact, 1, 8);
        rowact += __shfl_xor(rowact, 2, 8);
        rowact += __shfl_xor(rowact, 4, 8);

        float probs[8], mask[8];
        if (rowact > 0) {
            float m = -INFINITY;
#pragma unroll
            for (int i = 0; i < 8; ++i) m = fmaxf(m, active[i] ? gated[i] : -INFINITY);
            m = fmaxf(m, __shfl_xor(m, 1, 8));
            m = fmaxf(m, __shfl_xor(m, 2, 8));
            m = fmaxf(m, __shfl_xor(m, 4, 8));
            float s = 0.f;
#pragma unroll
            for (int i = 0; i < 8; ++i) {
                float ev = active[i] ? expf(gated[i] - m) : 0.f;
                probs[i] = ev; s += ev;
            }
            s += __shfl_xor(s, 1, 8);
            s += __shfl_xor(s, 2, 8);
            s += __shfl_xor(s, 4, 8);
            float rs = 1.0f / s;
#pragma unroll
            for (int i = 0; i < 8; ++i) {
                probs[i] *= rs;
                mask[i] = active[i] ? 1.f : 0.f;
            }
        } else {
            unsigned key[8];
#pragma unroll
            for (int i = 0; i < 8; ++i) key[i] = enc_key(logit[i]);
            unsigned cand = 0u;
            for (int bit = 31; bit >= 0; --bit) {
                unsigned test = cand | (1u << bit);
                int c = 0;
#pragma unroll
                for (int i = 0; i < 8; ++i) c += (key[i] >= test);
                c += __shfl_xor(c, 1, 8);
                c += __shfl_xor(c, 2, 8);
                c += __shfl_xor(c, 4, 8);
                if (c >= 32) cand = test;
            }
            int cgt = 0;
#pragma unroll
            for (int i = 0; i < 8; ++i) cgt += (key[i] > cand);
            cgt += __shfl_xor(cgt, 1, 8);
            cgt += __shfl_xor(cgt, 2, 8);
            cgt += __shfl_xor(cgt, 4, 8);
            int need_eq = 32 - cgt;

            int eqc = 0;
#pragma unroll
            for (int i = 0; i < 8; ++i) eqc += (key[i] == cand);
            int scan = eqc, tmp;
            tmp = __shfl_up(scan, 1, 8); if (eg >= 1) scan += tmp;
            tmp = __shfl_up(scan, 2, 8); if (eg >= 2) scan += tmp;
            tmp = __shfl_up(scan, 4, 8); if (eg >= 4) scan += tmp;
            int run = scan - eqc;   // ties with smaller global index
#pragma unroll
            for (int i = 0; i < 8; ++i) {
                int sel = (key[i] > cand) || ((key[i] == cand) && (run < need_eq));
                run += (key[i] == cand);
                mask[i]  = sel ? 1.f : 0.f;
                probs[i] = sel ? 0.03125f : 0.f;   // gated==0 on fallback rows
            }
        }

        const size_t row = (size_t)t * NEXP + e0;
        *(float4*)&out[row]                = make_float4(probs[0], probs[1], probs[2], probs[3]);
        *(float4*)&out[row + 4]            = make_float4(probs[4], probs[5], probs[6], probs[7]);
        *(float4*)&out[out_pre + row]      = make_float4(pre[0], pre[1], pre[2], pre[3]);
        *(float4*)&out[out_pre + row + 4]  = make_float4(pre[4], pre[5], pre[6], pre[7]);
        *(float4*)&out[out_mask + row]     = make_float4(mask[0], mask[1], mask[2], mask[3]);
        *(float4*)&out[out_mask + row + 4] = make_float4(mask[4], mask[5], mask[6], mask[7]);
    }
}

// ---------------- fallback (round-1 kernel, used only if ws too small) ----
#define TOKB    128
#define KC      64
#define XPAD    65

__global__ __launch_bounds__(256) void gate_kernel_fb(const float* __restrict__ x,
                                                      const float* __restrict__ sim,
                                                      const float* __restrict__ prep,
                                                      float* __restrict__ out) {
    __shared__ float x_lds[TOKB][XPAD];
    __shared__ float w_lds[KC][NEXP];
    __shared__ float ss_lds[TOKB];
    __shared__ float invcol[NEXP];
    __shared__ float thr_s[NEXP];

    const int tid = threadIdx.x;
    const int base_t = blockIdx.x * TOKB;

    if (tid < NEXP) { invcol[tid] = prep[tid]; thr_s[tid] = prep[64 + tid]; }
    if (tid < TOKB) ss_lds[tid] = 0.f;

    const int g_e = tid & 7;
    const int g_t = tid >> 3;
    const int e0 = g_e * 8;
    const int t0 = g_t * 4;

    const int lt = tid >> 4;
    const int lk = (tid & 15) * 4;

    float acc[4][8];
#pragma unroll
    for (int j = 0; j < 4; ++j)
#pragma unroll
        for (int i = 0; i < 8; ++i) acc[j][i] = 0.f;

    for (int kc = 0; kc < HID; kc += KC) {
        __syncthreads();
#pragma unroll
        for (int it = 0; it < 4; ++it) {
            int flat4 = it * 256 + tid;
            int k = flat4 >> 4;
            int e = (flat4 & 15) * 4;
            float4 v = *(const float4*)&sim[(size_t)(kc + k) * NEXP + e];
            v.x *= invcol[e]; v.y *= invcol[e + 1]; v.z *= invcol[e + 2]; v.w *= invcol[e + 3];
            *(float4*)&w_lds[k][e] = v;
        }
#pragma unroll
        for (int it = 0; it < 8; ++it) {
            int t = it * 16 + lt;
            float4 v = *(const float4*)&x[(size_t)(base_t + t) * HID + kc + lk];
            x_lds[t][lk + 0] = v.x; x_lds[t][lk + 1] = v.y;
            x_lds[t][lk + 2] = v.z; x_lds[t][lk + 3] = v.w;
            float s4 = v.x * v.x + v.y * v.y + v.z * v.z + v.w * v.w;
            s4 += __shfl_xor(s4, 1, 16);
            s4 += __shfl_xor(s4, 2, 16);
            s4 += __shfl_xor(s4, 4, 16);
            s4 += __shfl_xor(s4, 8, 16);
            if ((tid & 15) == 0) ss_lds[t] += s4;
        }
        __syncthreads();
#pragma unroll 8
        for (int k = 0; k < KC; ++k) {
            float x0 = x_lds[t0 + 0][k];
            float x1 = x_lds[t0 + 1][k];
            float x2 = x_lds[t0 + 2][k];
            float x3 = x_lds[t0 + 3][k];
            float4 w0 = *(const float4*)&w_lds[k][e0];
            float4 w1 = *(const float4*)&w_lds[k][e0 + 4];
            float wv[8] = { w0.x, w0.y, w0.z, w0.w, w1.x, w1.y, w1.z, w1.w };
#pragma unroll
            for (int i = 0; i < 8; ++i) {
                acc[0][i] += x0 * wv[i];
                acc[1][i] += x1 * wv[i];
                acc[2][i] += x2 * wv[i];
                acc[3][i] += x3 * wv[i];
            }
        }
    }

    const size_t out_pre  = (size_t)N_TOK * NEXP;
    const size_t out_mask = 2 * (size_t)N_TOK * NEXP;

#pragma unroll
    for (int j = 0; j < 4; ++j) {
        int t = t0 + j;
        float inv = 1.0f / fmaxf(sqrtf(ss_lds[t]), EPSF);
        float logit[8], pre[8], gated[8];
        int active[8];
        int myact = 0;
#pragma unroll
        for (int i = 0; i < 8; ++i) {
            logit[i] = acc[j][i] * inv;
            pre[i]   = logit[i] - thr_s[e0 + i];
            gated[i] = fmaxf(pre[i], 0.f);
            active[i] = pre[i] > 0.f;
            myact += active[i];
        }
        int rowact = myact;
        rowact += __shfl_xor(rowact, 1, 8);
        rowact += __shfl_xor(rowact, 2, 8);
        rowact += __shfl_xor(rowact, 4, 8);

        float probs[8], mask[8];
        if (rowact > 0) {
            float m = -INFINITY;
#pragma unroll
            for (int i = 0; i < 8; ++i) m = fmaxf(m, active[i] ? gated[i] : -INFINITY);
            m = fmaxf(m, __shfl_xor(m, 1, 8));
            m = fmaxf(m, __shfl_xor(m, 2, 8));
            m = fmaxf(m, __shfl_xor(m, 4, 8));
            float s = 0.f;
#pragma unroll
            for (int i = 0; i < 8; ++i) {
                float ev = active[i] ? expf(gated[i] - m) : 0.f;
                probs[i] = ev; s += ev;
            }
            s += __shfl_xor(s, 1, 8);
            s += __shfl_xor(s, 2, 8);
            s += __shfl_xor(s, 4, 8);
            float rs = 1.0f / s;
#pragma unroll
            for (int i = 0; i < 8; ++i) {
                probs[i] *= rs;
                mask[i] = active[i] ? 1.f : 0.f;
            }
        } else {
            unsigned key[8];
#pragma unroll
            for (int i = 0; i < 8; ++i) key[i] = enc_key(logit[i]);
            unsigned cand = 0u;
            for (int bit = 31; bit >= 0; --bit) {
                unsigned test = cand | (1u << bit);
                int c = 0;
#pragma unroll
                for (int i = 0; i < 8; ++i) c += (key[i] >= test);
                c += __shfl_xor(c, 1, 8);
                c += __shfl_xor(c, 2, 8);
                c += __shfl_xor(c, 4, 8);
                if (c >= 32) cand = test;
            }
            int cgt = 0;
#pragma unroll
            for (int i = 0; i < 8; ++i) cgt += (key[i] > cand);
            cgt += __shfl_xor(cgt, 1, 8);
            cgt += __shfl_xor(cgt, 2, 8);
            cgt += __shfl_xor(cgt, 4, 8);
            int need_eq = 32 - cgt;

            int eqc = 0;
#pragma unroll
            for (int i = 0; i < 8; ++i) eqc += (key[i] == cand);
            int scan = eqc, tmp;
            tmp = __shfl_up(scan, 1, 8); if (g_e >= 1) scan += tmp;
            tmp = __shfl_up(scan, 2, 8); if (g_e >= 2) scan += tmp;
            tmp = __shfl_up(scan, 4, 8); if (g_e >= 4) scan += tmp;
            int run = scan - eqc;
#pragma unroll
            for (int i = 0; i < 8; ++i) {
                int sel = (key[i] > cand) || ((key[i] == cand) && (run < need_eq));
                run += (key[i] == cand);
                mask[i]  = sel ? 1.f : 0.f;
                probs[i] = sel ? 0.03125f : 0.f;
            }
        }

        size_t row = (size_t)(base_t + t) * NEXP + e0;
        *(float4*)&out[row]                = make_float4(probs[0], probs[1], probs[2], probs[3]);
        *(float4*)&out[row + 4]            = make_float4(probs[4], probs[5], probs[6], probs[7]);
        *(float4*)&out[out_pre + row]      = make_float4(pre[0], pre[1], pre[2], pre[3]);
        *(float4*)&out[out_pre + row + 4]  = make_float4(pre[4], pre[5], pre[6], pre[7]);
        *(float4*)&out[out_mask + row]     = make_float4(mask[0], mask[1], mask[2], mask[3]);
        *(float4*)&out[out_mask + row + 4] = make_float4(mask[4], mask[5], mask[6], mask[7]);
    }
}

extern "C" void kernel_launch(void* const* d_in, const int* in_sizes, int n_in,
                              void* d_out, int out_size, void* d_ws, size_t ws_size,
                              hipStream_t stream) {
    (void)in_sizes; (void)n_in; (void)out_size;
    const float* x     = (const float*)d_in[0];
    const float* sim   = (const float*)d_in[1];
    const float* gates = (const float*)d_in[2];
    float* out = (float*)d_out;
    float* ws  = (float*)d_ws;

    hipLaunchKernelGGL(prep_kernel, dim3(1), dim3(256), 0, stream, sim, gates, ws);

    const size_t need = 512 + (size_t)HID * NEXP * sizeof(float);   // prep + wn2
    if (ws_size >= need) {
        float* wn2 = ws + 128;
        hipLaunchKernelGGL(prep2b_kernel, dim3(HID * NEXP / 256), dim3(256), 0, stream,
                           sim, ws, wn2);
        hipLaunchKernelGGL(gate_v15_kernel, dim3(N_TOK / 64), dim3(256), 0, stream,
                           x, wn2, ws, out);
    } else {
        hipLaunchKernelGGL(gate_kernel_fb, dim3(N_TOK / TOKB), dim3(256), 0, stream,
                           x, sim, ws, out);
    }
}